// Round 6
// baseline (257.162 us; speedup 1.0000x reference)
//
#include <hip/hip_runtime.h>
#include <hip/hip_bf16.h>

#define N 8192
#define D_IN 256
#define HID 512
#define Z 128
#define NCAT 16
#define EPS_F 1e-16f
#define GRID 384
#define PAD32 8960     // perm32 allocation (ints); max used 8688+64 slack
#define MAXT32 272     // max 32-row i-tiles: (8192+16*31)/32

typedef short bf16x8 __attribute__((ext_vector_type(8)));
typedef float f32x4 __attribute__((ext_vector_type(4)));

__device__ __forceinline__ unsigned short f2bf(float f) {
    unsigned u = __float_as_uint(f);
    unsigned r = u + 0x7FFFu + ((u >> 16) & 1u);
    return (unsigned short)(r >> 16);
}
__device__ __forceinline__ float bf2f(unsigned short s) {
    return __uint_as_float(((unsigned)s) << 16);
}
__device__ __forceinline__ unsigned pack2(float a, float b) {
    return (unsigned)f2bf(a) | ((unsigned)f2bf(b) << 16);
}
__device__ __forceinline__ float softplus_f(float x) {
    return fmaxf(x, 0.f) + log1pf(expf(-fabsf(x)));
}

struct KParams {
    const float* x; const int* c; const float* z;
    const float* W1; const float* b1; const float* W2; const float* b2;
    const float* Wz; const float* bz; const float* ws;
    float* out;
    unsigned short *H, *fzb, *W1t, *Wzt, *wsT, *WcT;
    float *bc;
    int *perm32, *cnt, *offs32, *tcat, *bar;
};

// manual grid barrier: counters zeroed by hipMemsetAsync before each launch.
__device__ __forceinline__ void gsync(int* bar, int slot, int nb) {
    __threadfence();
    __syncthreads();
    if (threadIdx.x == 0) {
        atomicAdd(&bar[slot], 1);
        while (__hip_atomic_load(&bar[slot], __ATOMIC_RELAXED, __HIP_MEMORY_SCOPE_AGENT) < nb)
            __builtin_amdgcn_s_sleep(2);
    }
    __syncthreads();
    __threadfence();
}

// fp32 [R][C] 32x32 tile -> bf16 transposed [C][R]
__device__ __forceinline__ void transpose32(
    const float* in, unsigned short* out, int R, int C, int r0, int c0, char* SAc) {
    float (*tile)[33] = (float (*)[33])SAc;
    int tx = threadIdx.x & 31, ty = threadIdx.x >> 5;
#pragma unroll
    for (int q = 0; q < 4; q++)
        tile[ty + 8 * q][tx] = in[(size_t)(r0 + ty + 8 * q) * C + c0 + tx];
    __syncthreads();
#pragma unroll
    for (int q = 0; q < 4; q++)
        out[(size_t)(c0 + ty + 8 * q) * R + r0 + tx] = f2bf(tile[tx][ty + 8 * q]);
}

// MFMA GEMM tile: C = act(A @ Bt^T + bias), BM=128 BN=64 BK=64, 4 waves 2x2.
template<bool A_F32, bool B_F32, bool RELU>
__device__ __forceinline__ void gemm_body(
    const void* __restrict__ Ap, const void* __restrict__ Btp,
    const float* __restrict__ bias, unsigned short* __restrict__ Cb,
    int Nn, int K, int row0, int col0, char* As, char* Bs) {
    int t = threadIdx.x;
    int wave = t >> 6, l = t & 63, l15 = l & 15, lg = l >> 4;
    int wm = (wave >> 1) * 64, wn = (wave & 1) * 32;
    f32x4 acc[4][2] = {};

    for (int kk0 = 0; kk0 < K; kk0 += 64) {
#pragma unroll
        for (int q = 0; q < 4; q++) {   // A: 128 rows x 8 chunks
            int cid = t + q * 256, row = cid >> 3, ch = cid & 7;
            uint4 w;
            if (A_F32) {
                const float* g = (const float*)Ap + (size_t)(row0 + row) * K + kk0 + ch * 8;
                float4 a0 = *(const float4*)g, a1 = *(const float4*)(g + 4);
                w.x = pack2(a0.x, a0.y); w.y = pack2(a0.z, a0.w);
                w.z = pack2(a1.x, a1.y); w.w = pack2(a1.z, a1.w);
            } else {
                w = *(const uint4*)((const unsigned short*)Ap + (size_t)(row0 + row) * K + kk0 + ch * 8);
            }
            *(uint4*)(As + row * 128 + ((ch ^ (row & 7)) << 4)) = w;
        }
#pragma unroll
        for (int q = 0; q < 2; q++) {   // B: 64 rows x 8 chunks
            int cid = t + q * 256, row = cid >> 3, ch = cid & 7;
            uint4 w;
            if (B_F32) {
                const float* g = (const float*)Btp + (size_t)(col0 + row) * K + kk0 + ch * 8;
                float4 a0 = *(const float4*)g, a1 = *(const float4*)(g + 4);
                w.x = pack2(a0.x, a0.y); w.y = pack2(a0.z, a0.w);
                w.z = pack2(a1.x, a1.y); w.w = pack2(a1.z, a1.w);
            } else {
                w = *(const uint4*)((const unsigned short*)Btp + (size_t)(col0 + row) * K + kk0 + ch * 8);
            }
            *(uint4*)(Bs + row * 128 + ((ch ^ (row & 7)) << 4)) = w;
        }
        __syncthreads();
#pragma unroll
        for (int kk = 0; kk < 2; kk++) {
            int ch = kk * 4 + lg;
            bf16x8 a[4], bq[2];
#pragma unroll
            for (int m = 0; m < 4; m++) {
                int ra = wm + m * 16 + l15;
                a[m] = *(const bf16x8*)(As + ra * 128 + ((ch ^ (ra & 7)) << 4));
            }
#pragma unroll
            for (int n2 = 0; n2 < 2; n2++) {
                int rb = wn + n2 * 16 + l15;
                bq[n2] = *(const bf16x8*)(Bs + rb * 128 + ((ch ^ (rb & 7)) << 4));
            }
#pragma unroll
            for (int m = 0; m < 4; m++)
#pragma unroll
                for (int n2 = 0; n2 < 2; n2++)
                    acc[m][n2] = __builtin_amdgcn_mfma_f32_16x16x32_bf16(a[m], bq[n2], acc[m][n2], 0, 0, 0);
        }
        __syncthreads();
    }
#pragma unroll
    for (int m = 0; m < 4; m++)
#pragma unroll
        for (int n2 = 0; n2 < 2; n2++)
#pragma unroll
            for (int r = 0; r < 4; r++) {
                int row = row0 + wm + m * 16 + lg * 4 + r;
                int col = col0 + wn + n2 * 16 + l15;
                float v = acc[m][n2][r] + (bias ? bias[col] : 0.f);
                if (RELU) v = fmaxf(v, 0.f);
                Cb[(size_t)row * Nn + col] = f2bf(v);
            }
}

__global__ __launch_bounds__(256, 2) void fused_all(KParams P) {
    __shared__ char SA[16384];
    __shared__ char SB[16384];
    __shared__ char UL[8192];      // u tile bf16 [32][128], swizzled
    __shared__ char FI[8192];      // fz i-rows bf16 [32][128], swizzled
    __shared__ float Tl[32];
    __shared__ float negpart[4][32];
    __shared__ int sIp[32];
    __shared__ int jp[64];
    __shared__ int sTmp[128];

    int t = threadIdx.x, b = blockIdx.x;
    int wv = t >> 6, l = t & 63, l15 = l & 15, lg = l >> 4;

    // ================= Phase A: transposes | bc | setup =================
    for (int un = b; un < 417; un += GRID) {
        if (un < 128) {
            transpose32(P.W1, P.W1t, D_IN, HID, (un >> 4) * 32, (un & 15) * 32, SA);
        } else if (un < 144) {
            int q = un - 128;
            transpose32(P.Wz, P.Wzt, Z, Z, (q >> 2) * 32, (q & 3) * 32, SA);
        } else if (un < 400) {
            int q = un - 144; int m = q >> 4; q &= 15;
            transpose32(P.ws + (size_t)m * Z * Z, P.wsT + (size_t)m * Z * Z, Z, Z,
                        (q >> 2) * 32, (q & 3) * 32, SA);
        } else if (un < 416) {
            int cat = un - 400;            // bc[cat][e] = sum_d b2[d]*ws[cat][d][e]
            if (t < Z) {
                float s = 0.f;
                for (int d = 0; d < Z; d++) s += P.b2[d] * P.ws[(size_t)cat * Z * Z + d * Z + t];
                P.bc[cat * Z + t] = s;
            }
        } else {
            // setup: count / scan(32-pad) / tile_cat / perm fill / pads
            for (int i = t; i < 128; i += 256) sTmp[i] = 0;
            __syncthreads();
            for (int n = t; n < N; n += 256) atomicAdd(&sTmp[(t >> 6) * 17 + P.c[n]], 1);
            __syncthreads();
            if (t < 16) {
                int s = 0;
                for (int w = 0; w < 4; w++) s += sTmp[w * 17 + t];
                sTmp[68 + t] = s;
                P.cnt[t] = s;
            }
            __syncthreads();
            if (t == 0) {
                int sp = 0;
                for (int k = 0; k < NCAT; k++) { sTmp[84 + k] = sp; sp += ((sTmp[68 + k] + 31) >> 5) << 5; }
                sTmp[100] = sp;
            }
            __syncthreads();
            if (t < 17) P.offs32[t] = sTmp[84 + t];
            for (int q = t; q < MAXT32; q += 256) {
                int cat = -1;
                for (int k = 0; k < NCAT; k++)
                    if (q * 32 >= sTmp[84 + k] && q * 32 < sTmp[84 + k + 1]) cat = k;
                P.tcat[q] = cat;
            }
            if (t < 16) {                       // pad slots -> -1
                for (int i = sTmp[84 + t] + sTmp[68 + t]; i < sTmp[84 + t + 1]; i++) P.perm32[i] = -1;
            }
            if (t >= 64 && t < 128) P.perm32[sTmp[100] + t - 64] = -1;   // 64 slack
            __syncthreads();
            for (int n = t; n < N; n += 256) {
                int cat = P.c[n];
                int pos = atomicAdd(&sTmp[101 + cat], 1);
                P.perm32[sTmp[84 + cat] + pos] = n;
            }
        }
        __syncthreads();
    }
    gsync(P.bar, 0, GRID);

    // ================= Phase B: gemm1(H) | fz | WcT (768 units, 2/block) ==========
    for (int un = b; un < 768; un += GRID) {
        if (un < 512) {
            gemm_body<true, false, true>(P.x, P.W1t, P.b1, P.H, HID, D_IN,
                                         (un >> 3) * 128, (un & 7) * 64, SA, SB);
        } else if (un < 640) {
            int q = un - 512;
            gemm_body<true, false, false>(P.z, P.Wzt, P.bz, P.fzb, Z, Z,
                                          (q >> 1) * 128, (q & 1) * 64, SA, SB);
        } else {
            int q = un - 640; int cat = q >> 3;
            gemm_body<false, true, false>(P.wsT + (size_t)cat * Z * Z, P.W2, nullptr,
                                          P.WcT + (size_t)cat * Z * HID, HID, Z,
                                          0, (q & 7) * 64, SA, SB);
        }
        __syncthreads();
    }
    gsync(P.bar, 1, GRID);

    // ================= Phase C: per i-tile (32 rows): u -> T -> neg -> out ========
    int cat = (b < MAXT32) ? P.tcat[b] : -1;
    if (cat < 0) return;
    int ibase = b * 32;
    if (t < 32) sIp[t] = P.perm32[ibase + t];
    __syncthreads();

    // ---- u = H[perm rows] @ WcT[cat]^T + bc : 32x128, K=512 ----
    const unsigned short* Wc = P.WcT + (size_t)cat * Z * HID;
    {
        f32x4 acc[2][2] = {};
        for (int kk0 = 0; kk0 < HID; kk0 += 64) {
            {
                int row = t >> 3, ch = t & 7;
                int pi = sIp[row];
                uint4 w = make_uint4(0, 0, 0, 0);
                if (pi >= 0) w = *(const uint4*)(P.H + (size_t)pi * HID + kk0 + ch * 8);
                *(uint4*)(SA + row * 128 + ((ch ^ (row & 7)) << 4)) = w;
            }
#pragma unroll
            for (int q = 0; q < 4; q++) {
                int cid = t + q * 256, row = cid >> 3, ch = cid & 7;
                uint4 wb = *(const uint4*)(Wc + (size_t)row * HID + kk0 + ch * 8);
                *(uint4*)(SB + row * 128 + ((ch ^ (row & 7)) << 4)) = wb;
            }
            __syncthreads();
#pragma unroll
            for (int kk = 0; kk < 2; kk++) {
                int ch = kk * 4 + lg;
                bf16x8 a[2], bb[2];
#pragma unroll
                for (int m = 0; m < 2; m++) {
                    int ra = m * 16 + l15;
                    a[m] = *(const bf16x8*)(SA + ra * 128 + ((ch ^ (ra & 7)) << 4));
                }
#pragma unroll
                for (int n2 = 0; n2 < 2; n2++) {
                    int rb = wv * 32 + n2 * 16 + l15;
                    bb[n2] = *(const bf16x8*)(SB + rb * 128 + ((ch ^ (rb & 7)) << 4));
                }
#pragma unroll
                for (int m = 0; m < 2; m++)
#pragma unroll
                    for (int n2 = 0; n2 < 2; n2++)
                        acc[m][n2] = __builtin_amdgcn_mfma_f32_16x16x32_bf16(a[m], bb[n2], acc[m][n2], 0, 0, 0);
            }
            __syncthreads();
        }
        // write u (+bc) into UL, swizzled
#pragma unroll
        for (int m = 0; m < 2; m++)
#pragma unroll
            for (int n2 = 0; n2 < 2; n2++)
#pragma unroll
                for (int r = 0; r < 4; r++) {
                    int rowd = m * 16 + lg * 4 + r;
                    int cold = wv * 32 + n2 * 16 + l15;
                    float v = acc[m][n2][r] + P.bc[cat * Z + cold];
                    int cj = cold >> 3;
                    *(unsigned short*)(UL + rowd * 256 + ((cj ^ (rowd & 7)) << 4) + (cold & 7) * 2) = f2bf(v);
                }
    }
    // stage fz i-rows
#pragma unroll
    for (int q = 0; q < 2; q++) {
        int cid = t + q * 256, row = cid >> 4, ch = cid & 15;
        int pi = sIp[row];
        uint4 w = make_uint4(0, 0, 0, 0);
        if (pi >= 0) w = *(const uint4*)(P.fzb + (size_t)pi * Z + ch * 8);
        *(uint4*)(FI + row * 256 + ((ch ^ (row & 7)) << 4)) = w;
    }
    __syncthreads();
    // T-dot: row = t>>3, 16 z per thread, reduce over 8 lanes
    {
        int row = t >> 3, l8 = t & 7;
        float dot = 0.f;
#pragma unroll
        for (int j = 0; j < 2; j++) {
            int cj = l8 * 2 + j;
            bf16x8 uu = *(const bf16x8*)(UL + row * 256 + ((cj ^ (row & 7)) << 4));
            bf16x8 ff = *(const bf16x8*)(FI + row * 256 + ((cj ^ (row & 7)) << 4));
#pragma unroll
            for (int e = 0; e < 8; e++) dot += bf2f((unsigned short)uu[e]) * bf2f((unsigned short)ff[e]);
        }
        dot += __shfl_xor(dot, 1, 8);
        dot += __shfl_xor(dot, 2, 8);
        dot += __shfl_xor(dot, 4, 8);
        if (l8 == 0) Tl[row] = dot;
    }
    // ---- neg: loop 64-j chunks of this category ----
    float rsum[2][4] = {};
    int jbase0 = P.offs32[cat], jend = P.offs32[cat + 1];
    for (int jbase = jbase0; jbase < jend; jbase += 64) {
        __syncthreads();
#pragma unroll
        for (int q = 0; q < 4; q++) {
            int cid = t + q * 256, row = cid >> 4, ch = cid & 15;
            int jidx = jbase + row;
            int pj = (jidx < jend) ? P.perm32[jidx] : -1;
            uint4 w = make_uint4(0, 0, 0, 0);
            if (pj >= 0) w = *(const uint4*)(P.fzb + (size_t)pj * Z + ch * 8);
            *(uint4*)(SB + row * 256 + ((ch ^ (row & 7)) << 4)) = w;
            if (ch == 0) jp[row] = pj;
        }
        __syncthreads();
        f32x4 a2[2] = {};
#pragma unroll
        for (int kk = 0; kk < 4; kk++) {
            int ch = kk * 4 + lg;
            bf16x8 a[2];
#pragma unroll
            for (int m = 0; m < 2; m++) {
                int ra = m * 16 + l15;
                a[m] = *(const bf16x8*)(UL + ra * 256 + ((ch ^ (ra & 7)) << 4));
            }
            int rb = wv * 16 + l15;
            bf16x8 bb = *(const bf16x8*)(SB + rb * 256 + ((ch ^ (rb & 7)) << 4));
            a2[0] = __builtin_amdgcn_mfma_f32_16x16x32_bf16(a[0], bb, a2[0], 0, 0, 0);
            a2[1] = __builtin_amdgcn_mfma_f32_16x16x32_bf16(a[1], bb, a2[1], 0, 0, 0);
        }
        bool jv = jp[wv * 16 + l15] >= 0;
#pragma unroll
        for (int m = 0; m < 2; m++)
#pragma unroll
            for (int r = 0; r < 4; r++)
                rsum[m][r] += jv ? softplus_f(a2[m][r]) : 0.f;
    }
    // reduce rsum over the wave's 16 j-cols, combine 4 waves, finalize
#pragma unroll
    for (int m = 0; m < 2; m++)
#pragma unroll
        for (int r = 0; r < 4; r++) {
            float v = rsum[m][r];
            v += __shfl_xor(v, 1, 16);
            v += __shfl_xor(v, 2, 16);
            v += __shfl_xor(v, 4, 16);
            v += __shfl_xor(v, 8, 16);
            if (l15 == 0) negpart[wv][m * 16 + lg * 4 + r] = v;
        }
    __syncthreads();
    if (t < 32) {
        int pi = sIp[t];
        if (pi >= 0) {
            float ns = negpart[0][t] + negpart[1][t] + negpart[2][t] + negpart[3][t];
            float nT = ns / (float)P.cnt[cat];
            float Ts = softplus_f(Tl[t]);
            P.out[pi] = logf(Ts + EPS_F) - logf(nT + EPS_F);
        }
    }
}

extern "C" void kernel_launch(void* const* d_in, const int* in_sizes, int n_in,
                              void* d_out, int out_size, void* d_ws, size_t ws_size,
                              hipStream_t stream) {
    KParams P;
    P.x  = (const float*)d_in[0];
    P.c  = (const int*)d_in[1];
    P.z  = (const float*)d_in[2];
    P.W1 = (const float*)d_in[3];
    P.b1 = (const float*)d_in[4];
    P.W2 = (const float*)d_in[5];
    P.b2 = (const float*)d_in[6];
    P.Wz = (const float*)d_in[7];
    P.bz = (const float*)d_in[8];
    P.ws = (const float*)d_in[9];
    P.out = (float*)d_out;

    char* p = (char*)d_ws;
    P.H    = (unsigned short*)p; p += (size_t)N * HID * 2;
    P.fzb  = (unsigned short*)p; p += (size_t)N * Z * 2;
    P.W1t  = (unsigned short*)p; p += (size_t)D_IN * HID * 2;
    P.Wzt  = (unsigned short*)p; p += (size_t)Z * Z * 2;
    P.wsT  = (unsigned short*)p; p += (size_t)NCAT * Z * Z * 2;
    P.WcT  = (unsigned short*)p; p += (size_t)NCAT * Z * HID * 2;
    P.bc   = (float*)p;          p += (size_t)NCAT * Z * 4;
    P.perm32 = (int*)p;          p += (size_t)PAD32 * 4;
    P.cnt    = (int*)p;          p += 256;
    P.offs32 = (int*)p;          p += 256;
    P.tcat   = (int*)p;          p += 2048;
    P.bar    = (int*)p;          p += 256;

    hipMemsetAsync(P.bar, 0, 8 * sizeof(int), stream);
    fused_all<<<dim3(GRID), dim3(256), 0, stream>>>(P);
}

// Round 7
// 90.094 us; speedup vs baseline: 2.8544x; 2.8544x over previous
//
#include <hip/hip_runtime.h>
#include <hip/hip_bf16.h>

#define N 8192
#define D_IN 256
#define HID 512
#define Z 128
#define NCAT 16
#define EPS_F 1e-16f
#define PAD32 8960     // perm32 allocation (ints); max used 8688+64 slack
#define MAXT32 272     // max 32-row i-tiles: (8192+16*31)/32

typedef short bf16x8 __attribute__((ext_vector_type(8)));
typedef float f32x4 __attribute__((ext_vector_type(4)));

__device__ __forceinline__ unsigned short f2bf(float f) {
    unsigned u = __float_as_uint(f);
    unsigned r = u + 0x7FFFu + ((u >> 16) & 1u);
    return (unsigned short)(r >> 16);
}
__device__ __forceinline__ float bf2f(unsigned short s) {
    return __uint_as_float(((unsigned)s) << 16);
}
__device__ __forceinline__ unsigned pack2(float a, float b) {
    return (unsigned)f2bf(a) | ((unsigned)f2bf(b) << 16);
}
__device__ __forceinline__ float softplus_f(float x) {
    return fmaxf(x, 0.f) + log1pf(expf(-fabsf(x)));
}

struct KParams {
    const float* x; const int* c; const float* z;
    const float* W1; const float* b1; const float* W2; const float* b2;
    const float* Wz; const float* bz; const float* ws;
    float* out;
    unsigned short *H, *fzb, *W1t, *Wzt, *wsT, *WcT;
    float *bc;
    int *perm32, *cnt, *offs32, *tcat;
};

// fp32 [R][C] 32x32 tile -> bf16 transposed [C][R]
__device__ __forceinline__ void transpose32(
    const float* in, unsigned short* out, int R, int C, int r0, int c0, char* SAc) {
    float (*tile)[33] = (float (*)[33])SAc;
    int tx = threadIdx.x & 31, ty = threadIdx.x >> 5;
#pragma unroll
    for (int q = 0; q < 4; q++)
        tile[ty + 8 * q][tx] = in[(size_t)(r0 + ty + 8 * q) * C + c0 + tx];
    __syncthreads();
#pragma unroll
    for (int q = 0; q < 4; q++)
        out[(size_t)(c0 + ty + 8 * q) * R + r0 + tx] = f2bf(tile[tx][ty + 8 * q]);
}

// ================= kernel 1: transposes | bc | setup =================
__global__ __launch_bounds__(256) void k_prep(KParams P) {
    __shared__ char SA[4352];
    __shared__ int sTmp[128];
    int t = threadIdx.x, b = blockIdx.x;
    if (b < 128) {
        transpose32(P.W1, P.W1t, D_IN, HID, (b >> 4) * 32, (b & 15) * 32, SA);
    } else if (b < 144) {
        int q = b - 128;
        transpose32(P.Wz, P.Wzt, Z, Z, (q >> 2) * 32, (q & 3) * 32, SA);
    } else if (b < 400) {
        int q = b - 144; int m = q >> 4; q &= 15;
        transpose32(P.ws + (size_t)m * Z * Z, P.wsT + (size_t)m * Z * Z, Z, Z,
                    (q >> 2) * 32, (q & 3) * 32, SA);
    } else if (b < 416) {
        int cat = b - 400;              // bc[cat][e] = sum_d b2[d]*ws[cat][d][e]
        if (t < Z) {
            float s = 0.f;
            for (int d = 0; d < Z; d++) s += P.b2[d] * P.ws[(size_t)cat * Z * Z + d * Z + t];
            P.bc[cat * Z + t] = s;
        }
    } else {
        // setup: count / scan(32-pad) / tcat / perm32 fill / pads
        for (int i = t; i < 128; i += 256) sTmp[i] = 0;
        __syncthreads();
        for (int n = t; n < N; n += 256) atomicAdd(&sTmp[(t >> 6) * 17 + P.c[n]], 1);
        __syncthreads();
        if (t < 16) {
            int s = 0;
            for (int w = 0; w < 4; w++) s += sTmp[w * 17 + t];
            sTmp[68 + t] = s;
            P.cnt[t] = s;
        }
        __syncthreads();
        if (t == 0) {
            int sp = 0;
            for (int k = 0; k < NCAT; k++) { sTmp[84 + k] = sp; sp += ((sTmp[68 + k] + 31) >> 5) << 5; }
            sTmp[100] = sp;
        }
        __syncthreads();
        if (t < 17) P.offs32[t] = sTmp[84 + t];
        for (int q = t; q < MAXT32; q += 256) {
            int cat = -1;
            for (int k = 0; k < NCAT; k++)
                if (q * 32 >= sTmp[84 + k] && q * 32 < sTmp[84 + k + 1]) cat = k;
            P.tcat[q] = cat;
        }
        if (t < 16) {                       // per-category tail pad -> -1
            for (int i = sTmp[84 + t] + sTmp[68 + t]; i < sTmp[84 + t + 1]; i++) P.perm32[i] = -1;
        }
        if (t >= 64 && t < 128) P.perm32[sTmp[100] + t - 64] = -1;   // 64 slack
        __syncthreads();
        for (int n = t; n < N; n += 256) {
            int cat = P.c[n];
            int pos = atomicAdd(&sTmp[101 + cat], 1);
            P.perm32[sTmp[84 + cat] + pos] = n;
        }
    }
}

// MFMA GEMM tile: C = act(A @ Bt^T + bias), BM=128 BN=64 BK=64, 4 waves 2x2.
template<bool A_F32, bool B_F32, bool RELU>
__device__ __forceinline__ void gemm_body(
    const void* __restrict__ Ap, const void* __restrict__ Btp,
    const float* __restrict__ bias, unsigned short* __restrict__ Cb,
    int Nn, int K, int row0, int col0, char* As, char* Bs) {
    int t = threadIdx.x;
    int wave = t >> 6, l = t & 63, l15 = l & 15, lg = l >> 4;
    int wm = (wave >> 1) * 64, wn = (wave & 1) * 32;
    f32x4 acc[4][2] = {};

    for (int kk0 = 0; kk0 < K; kk0 += 64) {
#pragma unroll
        for (int q = 0; q < 4; q++) {   // A: 128 rows x 8 chunks
            int cid = t + q * 256, row = cid >> 3, ch = cid & 7;
            uint4 w;
            if (A_F32) {
                const float* g = (const float*)Ap + (size_t)(row0 + row) * K + kk0 + ch * 8;
                float4 a0 = *(const float4*)g, a1 = *(const float4*)(g + 4);
                w.x = pack2(a0.x, a0.y); w.y = pack2(a0.z, a0.w);
                w.z = pack2(a1.x, a1.y); w.w = pack2(a1.z, a1.w);
            } else {
                w = *(const uint4*)((const unsigned short*)Ap + (size_t)(row0 + row) * K + kk0 + ch * 8);
            }
            *(uint4*)(As + row * 128 + ((ch ^ (row & 7)) << 4)) = w;
        }
#pragma unroll
        for (int q = 0; q < 2; q++) {   // B: 64 rows x 8 chunks
            int cid = t + q * 256, row = cid >> 3, ch = cid & 7;
            uint4 w;
            if (B_F32) {
                const float* g = (const float*)Btp + (size_t)(col0 + row) * K + kk0 + ch * 8;
                float4 a0 = *(const float4*)g, a1 = *(const float4*)(g + 4);
                w.x = pack2(a0.x, a0.y); w.y = pack2(a0.z, a0.w);
                w.z = pack2(a1.x, a1.y); w.w = pack2(a1.z, a1.w);
            } else {
                w = *(const uint4*)((const unsigned short*)Btp + (size_t)(col0 + row) * K + kk0 + ch * 8);
            }
            *(uint4*)(Bs + row * 128 + ((ch ^ (row & 7)) << 4)) = w;
        }
        __syncthreads();
#pragma unroll
        for (int kk = 0; kk < 2; kk++) {
            int ch = kk * 4 + lg;
            bf16x8 a[4], bq[2];
#pragma unroll
            for (int m = 0; m < 4; m++) {
                int ra = wm + m * 16 + l15;
                a[m] = *(const bf16x8*)(As + ra * 128 + ((ch ^ (ra & 7)) << 4));
            }
#pragma unroll
            for (int n2 = 0; n2 < 2; n2++) {
                int rb = wn + n2 * 16 + l15;
                bq[n2] = *(const bf16x8*)(Bs + rb * 128 + ((ch ^ (rb & 7)) << 4));
            }
#pragma unroll
            for (int m = 0; m < 4; m++)
#pragma unroll
                for (int n2 = 0; n2 < 2; n2++)
                    acc[m][n2] = __builtin_amdgcn_mfma_f32_16x16x32_bf16(a[m], bq[n2], acc[m][n2], 0, 0, 0);
        }
        __syncthreads();
    }
#pragma unroll
    for (int m = 0; m < 4; m++)
#pragma unroll
        for (int n2 = 0; n2 < 2; n2++)
#pragma unroll
            for (int r = 0; r < 4; r++) {
                int row = row0 + wm + m * 16 + lg * 4 + r;
                int col = col0 + wn + n2 * 16 + l15;
                float v = acc[m][n2][r] + (bias ? bias[col] : 0.f);
                if (RELU) v = fmaxf(v, 0.f);
                Cb[(size_t)row * Nn + col] = f2bf(v);
            }
}

// ================= kernel 2: gemm1(H) | fz | WcT =================
__global__ __launch_bounds__(256, 2) void k_mid(KParams P) {
    __shared__ char SA[16384];
    __shared__ char SB[16384];
    int b = blockIdx.x;
    if (b < 512) {
        gemm_body<true, false, true>(P.x, P.W1t, P.b1, P.H, HID, D_IN,
                                     (b >> 3) * 128, (b & 7) * 64, SA, SB);
    } else if (b < 640) {
        int q = b - 512;
        gemm_body<true, false, false>(P.z, P.Wzt, P.bz, P.fzb, Z, Z,
                                      (q >> 1) * 128, (q & 1) * 64, SA, SB);
    } else {
        int q = b - 640; int cat = q >> 3;
        gemm_body<false, true, false>(P.wsT + (size_t)cat * Z * Z, P.W2, nullptr,
                                      P.WcT + (size_t)cat * Z * HID, HID, Z,
                                      0, (q & 7) * 64, SA, SB);
    }
}

// ================= kernel 3: per i-tile (32 rows): u -> T -> neg -> out ========
__global__ __launch_bounds__(256, 2) void k_tail(KParams P) {
    __shared__ char SA[16384];
    __shared__ char SB[16384];
    __shared__ char UL[8192];      // u tile bf16 [32][128], swizzled
    __shared__ char FI[8192];      // fz i-rows bf16 [32][128], swizzled
    __shared__ float Tl[32];
    __shared__ float negpart[4][32];
    __shared__ int sIp[32];
    __shared__ int jp[64];

    int t = threadIdx.x, b = blockIdx.x;
    int wv = t >> 6, l = t & 63, l15 = l & 15, lg = l >> 4;

    int cat = (b < MAXT32) ? P.tcat[b] : -1;
    if (cat < 0) return;
    int ibase = b * 32;
    if (t < 32) sIp[t] = P.perm32[ibase + t];
    __syncthreads();

    // ---- u = H[perm rows] @ WcT[cat]^T + bc : 32x128, K=512 ----
    const unsigned short* Wc = P.WcT + (size_t)cat * Z * HID;
    {
        f32x4 acc[2][2] = {};
        for (int kk0 = 0; kk0 < HID; kk0 += 64) {
            {
                int row = t >> 3, ch = t & 7;
                int pi = sIp[row];
                uint4 w = make_uint4(0, 0, 0, 0);
                if (pi >= 0) w = *(const uint4*)(P.H + (size_t)pi * HID + kk0 + ch * 8);
                *(uint4*)(SA + row * 128 + ((ch ^ (row & 7)) << 4)) = w;
            }
#pragma unroll
            for (int q = 0; q < 4; q++) {
                int cid = t + q * 256, row = cid >> 3, ch = cid & 7;
                uint4 wb = *(const uint4*)(Wc + (size_t)row * HID + kk0 + ch * 8);
                *(uint4*)(SB + row * 128 + ((ch ^ (row & 7)) << 4)) = wb;
            }
            __syncthreads();
#pragma unroll
            for (int kk = 0; kk < 2; kk++) {
                int ch = kk * 4 + lg;
                bf16x8 a[2], bb[2];
#pragma unroll
                for (int m = 0; m < 2; m++) {
                    int ra = m * 16 + l15;
                    a[m] = *(const bf16x8*)(SA + ra * 128 + ((ch ^ (ra & 7)) << 4));
                }
#pragma unroll
                for (int n2 = 0; n2 < 2; n2++) {
                    int rb = wv * 32 + n2 * 16 + l15;
                    bb[n2] = *(const bf16x8*)(SB + rb * 128 + ((ch ^ (rb & 7)) << 4));
                }
#pragma unroll
                for (int m = 0; m < 2; m++)
#pragma unroll
                    for (int n2 = 0; n2 < 2; n2++)
                        acc[m][n2] = __builtin_amdgcn_mfma_f32_16x16x32_bf16(a[m], bb[n2], acc[m][n2], 0, 0, 0);
            }
            __syncthreads();
        }
        // write u (+bc) into UL, swizzled
#pragma unroll
        for (int m = 0; m < 2; m++)
#pragma unroll
            for (int n2 = 0; n2 < 2; n2++)
#pragma unroll
                for (int r = 0; r < 4; r++) {
                    int rowd = m * 16 + lg * 4 + r;
                    int cold = wv * 32 + n2 * 16 + l15;
                    float v = acc[m][n2][r] + P.bc[cat * Z + cold];
                    int cj = cold >> 3;
                    *(unsigned short*)(UL + rowd * 256 + ((cj ^ (rowd & 7)) << 4) + (cold & 7) * 2) = f2bf(v);
                }
    }
    // stage fz i-rows
#pragma unroll
    for (int q = 0; q < 2; q++) {
        int cid = t + q * 256, row = cid >> 4, ch = cid & 15;
        int pi = sIp[row];
        uint4 w = make_uint4(0, 0, 0, 0);
        if (pi >= 0) w = *(const uint4*)(P.fzb + (size_t)pi * Z + ch * 8);
        *(uint4*)(FI + row * 256 + ((ch ^ (row & 7)) << 4)) = w;
    }
    __syncthreads();
    // T-dot: row = t>>3, 16 z per thread, reduce over 8 lanes
    {
        int row = t >> 3, l8 = t & 7;
        float dot = 0.f;
#pragma unroll
        for (int j = 0; j < 2; j++) {
            int cj = l8 * 2 + j;
            bf16x8 uu = *(const bf16x8*)(UL + row * 256 + ((cj ^ (row & 7)) << 4));
            bf16x8 ff = *(const bf16x8*)(FI + row * 256 + ((cj ^ (row & 7)) << 4));
#pragma unroll
            for (int e = 0; e < 8; e++) dot += bf2f((unsigned short)uu[e]) * bf2f((unsigned short)ff[e]);
        }
        dot += __shfl_xor(dot, 1, 8);
        dot += __shfl_xor(dot, 2, 8);
        dot += __shfl_xor(dot, 4, 8);
        if (l8 == 0) Tl[row] = dot;
    }
    // ---- neg: loop 64-j chunks of this category ----
    float rsum[2][4] = {};
    int jbase0 = P.offs32[cat], jend = P.offs32[cat + 1];
    for (int jbase = jbase0; jbase < jend; jbase += 64) {
        __syncthreads();
#pragma unroll
        for (int q = 0; q < 4; q++) {
            int cid = t + q * 256, row = cid >> 4, ch = cid & 15;
            int jidx = jbase + row;
            int pj = (jidx < jend) ? P.perm32[jidx] : -1;
            uint4 w = make_uint4(0, 0, 0, 0);
            if (pj >= 0) w = *(const uint4*)(P.fzb + (size_t)pj * Z + ch * 8);
            *(uint4*)(SB + row * 256 + ((ch ^ (row & 7)) << 4)) = w;
            if (ch == 0) jp[row] = pj;
        }
        __syncthreads();
        f32x4 a2[2] = {};
#pragma unroll
        for (int kk = 0; kk < 4; kk++) {
            int ch = kk * 4 + lg;
            bf16x8 a[2];
#pragma unroll
            for (int m = 0; m < 2; m++) {
                int ra = m * 16 + l15;
                a[m] = *(const bf16x8*)(UL + ra * 256 + ((ch ^ (ra & 7)) << 4));
            }
            int rb = wv * 16 + l15;
            bf16x8 bb = *(const bf16x8*)(SB + rb * 256 + ((ch ^ (rb & 7)) << 4));
            a2[0] = __builtin_amdgcn_mfma_f32_16x16x32_bf16(a[0], bb, a2[0], 0, 0, 0);
            a2[1] = __builtin_amdgcn_mfma_f32_16x16x32_bf16(a[1], bb, a2[1], 0, 0, 0);
        }
        bool jv = jp[wv * 16 + l15] >= 0;
#pragma unroll
        for (int m = 0; m < 2; m++)
#pragma unroll
            for (int r = 0; r < 4; r++)
                rsum[m][r] += jv ? softplus_f(a2[m][r]) : 0.f;
    }
    // reduce rsum over the wave's 16 j-cols, combine 4 waves, finalize
#pragma unroll
    for (int m = 0; m < 2; m++)
#pragma unroll
        for (int r = 0; r < 4; r++) {
            float v = rsum[m][r];
            v += __shfl_xor(v, 1, 16);
            v += __shfl_xor(v, 2, 16);
            v += __shfl_xor(v, 4, 16);
            v += __shfl_xor(v, 8, 16);
            if (l15 == 0) negpart[wv][m * 16 + lg * 4 + r] = v;
        }
    __syncthreads();
    if (t < 32) {
        int pi = sIp[t];
        if (pi >= 0) {
            float ns = negpart[0][t] + negpart[1][t] + negpart[2][t] + negpart[3][t];
            float nT = ns / (float)P.cnt[cat];
            float Ts = softplus_f(Tl[t]);
            P.out[pi] = logf(Ts + EPS_F) - logf(nT + EPS_F);
        }
    }
}

extern "C" void kernel_launch(void* const* d_in, const int* in_sizes, int n_in,
                              void* d_out, int out_size, void* d_ws, size_t ws_size,
                              hipStream_t stream) {
    KParams P;
    P.x  = (const float*)d_in[0];
    P.c  = (const int*)d_in[1];
    P.z  = (const float*)d_in[2];
    P.W1 = (const float*)d_in[3];
    P.b1 = (const float*)d_in[4];
    P.W2 = (const float*)d_in[5];
    P.b2 = (const float*)d_in[6];
    P.Wz = (const float*)d_in[7];
    P.bz = (const float*)d_in[8];
    P.ws = (const float*)d_in[9];
    P.out = (float*)d_out;

    char* p = (char*)d_ws;
    P.H    = (unsigned short*)p; p += (size_t)N * HID * 2;
    P.fzb  = (unsigned short*)p; p += (size_t)N * Z * 2;
    P.W1t  = (unsigned short*)p; p += (size_t)D_IN * HID * 2;
    P.Wzt  = (unsigned short*)p; p += (size_t)Z * Z * 2;
    P.wsT  = (unsigned short*)p; p += (size_t)NCAT * Z * Z * 2;
    P.WcT  = (unsigned short*)p; p += (size_t)NCAT * Z * HID * 2;
    P.bc   = (float*)p;          p += (size_t)NCAT * Z * 4;
    P.perm32 = (int*)p;          p += (size_t)PAD32 * 4;
    P.cnt    = (int*)p;          p += 256;
    P.offs32 = (int*)p;          p += 256;
    P.tcat   = (int*)p;          p += 2048;

    k_prep<<<dim3(417), dim3(256), 0, stream>>>(P);
    k_mid<<<dim3(768), dim3(256), 0, stream>>>(P);
    k_tail<<<dim3(MAXT32), dim3(256), 0, stream>>>(P);
}